// Round 1
// baseline (221.826 us; speedup 1.0000x reference)
//
#include <hip/hip_runtime.h>
#include <math.h>

#define B_  4096
#define T_  50
#define K_  32
#define D_  64
#define H_  256
#define HL_ 128
#define G4_ 512   // 4*HL

typedef __attribute__((ext_vector_type(8))) short bf16x8;
typedef __attribute__((ext_vector_type(4))) float f32x4;

__device__ __forceinline__ float fast_exp(float x){ return __expf(x); }
__device__ __forceinline__ float fast_rcp(float x){ return __builtin_amdgcn_rcpf(x); }
__device__ __forceinline__ float sigmoidf_(float x){ return fast_rcp(1.f + fast_exp(-x)); }
__device__ __forceinline__ float tanhf_(float x){ return 1.f - 2.f*fast_rcp(1.f + fast_exp(2.f*x)); }

__device__ __forceinline__ short f2bf(float f){
  union { float f; unsigned u; } v; v.f = f;
  unsigned r = v.u + 0x7FFFu + ((v.u >> 16) & 1u);   // round-to-nearest-even
  return (short)(r >> 16);
}
__device__ __forceinline__ float bf2f(short s){
  union { unsigned u; float f; } v; v.u = ((unsigned)(unsigned short)s) << 16;
  return v.f;
}

__device__ __forceinline__ float wave_reduce_sum(float v){
  #pragma unroll
  for (int off = 32; off; off >>= 1) v += __shfl_xor(v, off);
  return v;
}

// ---------------------------------------------------------------------------
// Kernel 1: per-student head. Unchanged from the 221.6us baseline (no head
// counters in top-5 yet; lstm is the target this round).
// ---------------------------------------------------------------------------
#define KROW 72
#define PROW 40

__global__ __launch_bounds__(256) void head_kernel(
    const int* __restrict__ uididx, const int* __restrict__ kcodeidx,
    const int* __restrict__ kcode_len, const float* __restrict__ qidemb,
    const int* __restrict__ qid_len, const float* __restrict__ stuE,
    const float* __restrict__ knE,
    const float* __restrict__ T_W1, const float* __restrict__ T_b1,
    const float* __restrict__ T_W2, const float* __restrict__ T_b2,
    const float* __restrict__ A_W1, const float* __restrict__ A_b1,
    const float* __restrict__ A_W2, const float* __restrict__ A_b2,
    short* __restrict__ bvec, float* __restrict__ t_val, float* __restrict__ a_val)
{
  __shared__ __align__(16) short s_kemb[K_*KROW];
  __shared__ __align__(16) short s_kembT[D_*PROW];
  __shared__ __align__(16) short s_p[64*PROW];
  __shared__ float s_stu[D_];
  __shared__ float s_mast[K_];
  __shared__ float s_kmf[K_];
  __shared__ float s_mvec[D_];
  __shared__ float s_avec[D_];
  __shared__ float s_redT[4];
  __shared__ float s_redA[4];

  const int b    = blockIdx.x;
  const int tid  = threadIdx.x;
  const int lane = tid & 63;
  const int w    = tid >> 6;
  const int l15  = lane & 15;
  const int quad = lane >> 4;
  const int klen = kcode_len[b];
  const int qlen = qid_len[b];

  if (tid < D_) s_stu[tid] = stuE[uididx[b]*D_ + tid];
  #pragma unroll
  for (int i = tid; i < 512; i += 256){
    int k = i >> 4, f4 = i & 15;
    const float4 v = *(const float4*)&knE[(size_t)kcodeidx[b*K_ + k]*D_ + f4*4];
    short4 b4; b4.x = f2bf(v.x); b4.y = f2bf(v.y); b4.z = f2bf(v.z); b4.w = f2bf(v.w);
    *(short4*)&s_kemb[k*KROW + f4*4] = b4;
    int d = f4*4;
    s_kembT[(d+0)*PROW + k] = b4.x;
    s_kembT[(d+1)*PROW + k] = b4.y;
    s_kembT[(d+2)*PROW + k] = b4.z;
    s_kembT[(d+3)*PROW + k] = b4.w;
  }
  __syncthreads();

  // mastery: 8 lanes per k, bank-rotated
  {
    int k = tid >> 3, l8 = tid & 7;
    float s = 0.f;
    #pragma unroll
    for (int j = 0; j < 8; ++j){
      int d = l8 + 8*((j + k) & 7);
      s += s_stu[d] * bf2f(s_kemb[k*KROW + d]);
    }
    s += __shfl_xor(s, 1); s += __shfl_xor(s, 2); s += __shfl_xor(s, 4);
    if (l8 == 0){
      float valid = (k < klen) ? 1.f : 0.f;
      s_mast[k] = valid * sigmoidf_(s * 0.2f);
      s_kmf[k]  = valid;
    }
  }
  __syncthreads();

  if (tid < D_){
    float mv = 0.f, av = 0.f;
    #pragma unroll 4
    for (int k = 0; k < K_; ++k){
      float e = bf2f(s_kemb[k*KROW + tid]);
      mv += s_mast[k] * e;
      av += s_kmf[k]  * e;
    }
    s_mvec[tid] = mv; s_avec[tid] = av;
  }
  __syncthreads();

  // ---- attention via MFMA; q A-frags straight from global ----
  {
    const int qrow = w*16 + l15;
    bf16x8 aq[2];
    #pragma unroll
    for (int kt = 0; kt < 2; ++kt){
      if (qrow < qlen){
        const float4 v0 = *(const float4*)&qidemb[((size_t)b*T_ + qrow)*D_ + kt*32 + quad*8];
        const float4 v1 = *(const float4*)&qidemb[((size_t)b*T_ + qrow)*D_ + kt*32 + quad*8 + 4];
        aq[kt][0]=f2bf(v0.x); aq[kt][1]=f2bf(v0.y); aq[kt][2]=f2bf(v0.z); aq[kt][3]=f2bf(v0.w);
        aq[kt][4]=f2bf(v1.x); aq[kt][5]=f2bf(v1.y); aq[kt][6]=f2bf(v1.z); aq[kt][7]=f2bf(v1.w);
      } else {
        aq[kt][0]=0; aq[kt][1]=0; aq[kt][2]=0; aq[kt][3]=0;
        aq[kt][4]=0; aq[kt][5]=0; aq[kt][6]=0; aq[kt][7]=0;
      }
    }
    f32x4 zero = {0.f, 0.f, 0.f, 0.f};
    f32x4 accs[2] = {zero, zero};
    #pragma unroll
    for (int kt = 0; kt < 2; ++kt){
      #pragma unroll
      for (int nt = 0; nt < 2; ++nt){
        bf16x8 bk = *(const bf16x8*)&s_kemb[(nt*16 + l15)*KROW + kt*32 + quad*8];
        accs[nt] = __builtin_amdgcn_mfma_f32_16x16x32_bf16(aq[kt], bk, accs[nt], 0, 0, 0);
      }
    }
    #pragma unroll
    for (int r = 0; r < 4; ++r){
      float v0 = (l15      < klen) ? accs[0][r]*0.15f : -1e9f;
      float v1 = (l15 + 16 < klen) ? accs[1][r]*0.15f : -1e9f;
      float mx = fmaxf(v0, v1);
      #pragma unroll
      for (int off = 1; off < 16; off <<= 1) mx = fmaxf(mx, __shfl_xor(mx, off));
      float e0 = fast_exp(v0 - mx), e1 = fast_exp(v1 - mx);
      float sm = e0 + e1;
      #pragma unroll
      for (int off = 1; off < 16; off <<= 1) sm += __shfl_xor(sm, off);
      float inv = fast_rcp(sm);
      int row = w*16 + quad*4 + r;
      s_p[row*PROW + l15]      = f2bf(e0 * inv);
      s_p[row*PROW + 16 + l15] = f2bf(e1 * inv);
    }
    bf16x8 ap = *(const bf16x8*)&s_p[(w*16 + l15)*PROW + quad*8];
    #pragma unroll
    for (int nt = 0; nt < 4; ++nt){
      bf16x8 bv = *(const bf16x8*)&s_kembT[(nt*16 + l15)*PROW + quad*8];
      f32x4 acco = __builtin_amdgcn_mfma_f32_16x16x32_bf16(ap, bv, zero, 0, 0, 0);
      #pragma unroll
      for (int r = 0; r < 4; ++r){
        int t = w*16 + quad*4 + r;
        if (t < qlen) bvec[((size_t)b*T_ + t)*D_ + nt*16 + l15] = f2bf(acco[r]);
      }
    }
  }

  // ---- both DNNs interleaved ----
  {
    float accT = T_b1[tid];
    float accA = A_b1[tid];
    #pragma unroll 4
    for (int d = 0; d < D_; ++d){
      float mv = s_mvec[d], av = s_avec[d];
      accT += mv * T_W1[d*H_ + tid];
      accA += av * A_W1[d*H_ + tid];
    }
    float termT = tanhf_(accT) * T_W2[tid];
    float termA = tanhf_(accA) * A_W2[tid];
    termT = wave_reduce_sum(termT);
    termA = wave_reduce_sum(termA);
    if (lane == 0){ s_redT[w] = termT; s_redA[w] = termA; }
    __syncthreads();
    if (tid == 0){
      t_val[b] = s_redT[0] + s_redT[1] + s_redT[2] + s_redT[3] + T_b2[0];
      float v = s_redA[0] + s_redA[1] + s_redA[2] + s_redA[3] + A_b2[0];
      a_val[b] = 8.f * (sigmoidf_(fabsf(v)) - 0.5f);
    }
  }
}

// ---------------------------------------------------------------------------
// Kernel 2: MFMA LSTM, R12: OPERAND-SWAPPED MFMA. mfma(W, A) instead of
// mfma(A, W) — A/B fragment lane-layouts are identical for 16x16x32, so wf/af
// are reused unchanged; only the C layout flips: each thread now owns ONE
// student (l15) x 4 consecutive gate cols (w*16+quad*4+r) instead of 4
// students x 1 col. Gains: (1) one length mask per thread (predicated, no
// 4x exec-mask regions), (2) h-store = one packed ds_write_b64 instead of
// 4x ds_write_b16 + 4x f2bf addressing, (3) t-loop unrolled x2 so xb/hb are
// compile-time and all LDS addresses are loop-invariant.
// Numerics bit-identical to R11 (same fp ops per element).
// ---------------------------------------------------------------------------
#define AROW 408   // shorts/row: x0(64)|x1(64)|h0(128)|h1(128)|pad(24)

__global__ __launch_bounds__(512) void lstm_kernel(
    const short* __restrict__ bvec, const int* __restrict__ qid_len,
    const float* __restrict__ L_Wi, const float* __restrict__ L_Wh,
    const float* __restrict__ L_b,  const float* __restrict__ L_Wo,
    const float* __restrict__ L_bo, const float* __restrict__ t_val,
    const float* __restrict__ a_val, float* __restrict__ out)
{
  __shared__ __align__(16) short s_A[16*AROW];
  __shared__ int s_len[16];

  const int tid  = threadIdx.x;
  const int s0   = blockIdx.x * 16;
  const int w    = tid >> 6;
  const int lane = tid & 63;
  const int l15  = lane & 15;
  const int quad = lane >> 4;

  // Weight fragments: col = g*128 + w*16 + l15, k = kt*32 + quad*8 + j.
  // Used as the MFMA *A* operand now (layout identical to B-fragment).
  bf16x8 wf[4][6];
  f32x4  biasv4[4];   // per-component bias: col = g*128 + w*16 + quad*4 + r
  #pragma unroll
  for (int g = 0; g < 4; ++g){
    const int col = g*128 + w*16 + l15;
    #pragma unroll
    for (int r = 0; r < 4; ++r) biasv4[g][r] = L_b[g*128 + w*16 + quad*4 + r];
    #pragma unroll
    for (int kt = 0; kt < 6; ++kt){
      #pragma unroll
      for (int j = 0; j < 8; ++j){
        int k = kt*32 + quad*8 + j;
        float v = (k < D_) ? L_Wi[k*G4_ + col] : L_Wh[(k-D_)*G4_ + col];
        wf[g][kt][j] = f2bf(v);
      }
    }
  }

  for (int p = tid; p < 16*AROW; p += 512) s_A[p] = 0;
  if (tid < 16) s_len[tid] = qid_len[s0 + tid];
  __syncthreads();

  const int xs = tid >> 5, xpos = tid & 31;
  {
    const short2 xv = *(const short2*)&bvec[((size_t)(s0+xs)*T_ + 0)*D_ + xpos*2];
    *(short2*)&s_A[xs*AROW + xpos*2] = xv;
  }
  int maxlen = 0;
  #pragma unroll
  for (int i = 0; i < 16; ++i) maxlen = max(maxlen, s_len[i]);
  const int mylen = s_len[l15];           // one mask per thread (student l15)
  float c_reg[4] = {0.f,0.f,0.f,0.f};
  float h_reg[4] = {0.f,0.f,0.f,0.f};

  short2 xv_reg;
  if (1 < maxlen) xv_reg = *(const short2*)&bvec[((size_t)(s0+xs)*T_ + 1)*D_ + xpos*2];
  __syncthreads();

#define LSTM_STEP(TI, XB) do {                                                 \
    const int xb_ = (XB); const int hb_ = xb_ ^ 1;                             \
    if ((TI) + 1 < maxlen) *(short2*)&s_A[xs*AROW + hb_*64 + xpos*2] = xv_reg; \
    if ((TI) + 2 < maxlen)                                                     \
      xv_reg = *(const short2*)&bvec[((size_t)(s0+xs)*T_ + ((TI)+2))*D_ + xpos*2]; \
    bf16x8 af[6];                                                              \
    af[0] = *(const bf16x8*)&s_A[l15*AROW + xb_*64 +      quad*8];             \
    af[1] = *(const bf16x8*)&s_A[l15*AROW + xb_*64 + 32 + quad*8];             \
    _Pragma("unroll")                                                          \
    for (int kt = 0; kt < 4; ++kt)                                             \
      af[2+kt] = *(const bf16x8*)&s_A[l15*AROW + 128 + hb_*128 + kt*32 + quad*8]; \
    f32x4 acc[4];                                                              \
    acc[0]=biasv4[0]; acc[1]=biasv4[1]; acc[2]=biasv4[2]; acc[3]=biasv4[3];    \
    _Pragma("unroll")                                                          \
    for (int kt = 0; kt < 6; ++kt){                                            \
      _Pragma("unroll")                                                        \
      for (int g = 0; g < 4; ++g)                                              \
        acc[g] = __builtin_amdgcn_mfma_f32_16x16x32_bf16(wf[g][kt], af[kt], acc[g], 0, 0, 0); \
    }                                                                          \
    const bool upd_ = (TI) < mylen;                                            \
    _Pragma("unroll")                                                          \
    for (int r = 0; r < 4; ++r){                                               \
      float gi = acc[0][r], gf = acc[1][r], gg = acc[2][r], go = acc[3][r];    \
      float c2 = sigmoidf_(gf)*c_reg[r] + sigmoidf_(gi)*tanhf_(gg);            \
      float h2 = sigmoidf_(go)*tanhf_(c2);                                     \
      c_reg[r] = upd_ ? c2 : c_reg[r];                                         \
      h_reg[r] = upd_ ? h2 : h_reg[r];                                         \
    }                                                                          \
    uint2 hp_;                                                                 \
    hp_.x = (unsigned)(unsigned short)f2bf(h_reg[0])                           \
          | ((unsigned)(unsigned short)f2bf(h_reg[1]) << 16);                  \
    hp_.y = (unsigned)(unsigned short)f2bf(h_reg[2])                           \
          | ((unsigned)(unsigned short)f2bf(h_reg[3]) << 16);                  \
    *(uint2*)&s_A[l15*AROW + 128 + xb_*128 + w*16 + quad*4] = hp_;             \
    __syncthreads();                                                           \
  } while(0)

  int t = 0;
  for (; t + 1 < maxlen; t += 2){
    LSTM_STEP(t,   0);
    LSTM_STEP(t+1, 1);
  }
  if (t < maxlen) LSTM_STEP(t, 0);
#undef LSTM_STEP

  const int xbLast = (maxlen - 1) & 1;
  for (int s2 = w; s2 < 16; s2 += 8){
    float h0 = bf2f(s_A[s2*AROW + 128 + xbLast*128 + lane]);
    float h1 = bf2f(s_A[s2*AROW + 128 + xbLast*128 + 64 + lane]);
    float part = h0*L_Wo[lane] + h1*L_Wo[64+lane];
    part = wave_reduce_sum(part);
    if (lane == 0){
      float bb = 8.f * (sigmoidf_(part + L_bo[0]) - 0.5f);
      out[s0+s2] = sigmoidf_(a_val[s0+s2] * (t_val[s0+s2] - bb));
    }
  }
}

// ---------------------------------------------------------------------------
extern "C" void kernel_launch(void* const* d_in, const int* in_sizes, int n_in,
                              void* d_out, int out_size, void* d_ws, size_t ws_size,
                              hipStream_t stream)
{
  (void)in_sizes; (void)n_in; (void)out_size; (void)ws_size;
  const int*   uididx    = (const int*)  d_in[0];
  const int*   kcodeidx  = (const int*)  d_in[1];
  const int*   kcode_len = (const int*)  d_in[2];
  const float* qidemb    = (const float*)d_in[3];
  const int*   qid_len   = (const int*)  d_in[4];
  const float* stuE      = (const float*)d_in[5];
  const float* knE       = (const float*)d_in[6];
  const float* T_W1      = (const float*)d_in[7];
  const float* T_b1      = (const float*)d_in[8];
  const float* T_W2      = (const float*)d_in[9];
  const float* T_b2      = (const float*)d_in[10];
  const float* A_W1      = (const float*)d_in[11];
  const float* A_b1      = (const float*)d_in[12];
  const float* A_W2      = (const float*)d_in[13];
  const float* A_b2      = (const float*)d_in[14];
  const float* L_Wi      = (const float*)d_in[15];
  const float* L_Wh      = (const float*)d_in[16];
  const float* L_b       = (const float*)d_in[17];
  const float* L_Wo      = (const float*)d_in[18];
  const float* L_bo      = (const float*)d_in[19];
  float* out = (float*)d_out;

  short* bvec  = (short*)d_ws;                       // B*T*D bf16 = 26.2 MB
  float* t_val = (float*)(bvec + (size_t)B_*T_*D_);  // B floats
  float* a_val = t_val + B_;                         // B floats

  hipLaunchKernelGGL(head_kernel, dim3(B_), dim3(256), 0, stream,
    uididx, kcodeidx, kcode_len, qidemb, qid_len, stuE, knE,
    T_W1, T_b1, T_W2, T_b2, A_W1, A_b1, A_W2, A_b2,
    bvec, t_val, a_val);

  hipLaunchKernelGGL(lstm_kernel, dim3(B_/16), dim3(512), 0, stream,
    bvec, qid_len, L_Wi, L_Wh, L_b, L_Wo, L_bo, t_val, a_val, out);
}

// Round 2
// 219.140 us; speedup vs baseline: 1.0123x; 1.0123x over previous
//
#include <hip/hip_runtime.h>
#include <math.h>

#define B_  4096
#define T_  50
#define K_  32
#define D_  64
#define H_  256
#define HL_ 128
#define G4_ 512   // 4*HL

typedef __attribute__((ext_vector_type(8))) short bf16x8;
typedef __attribute__((ext_vector_type(4))) float f32x4;

__device__ __forceinline__ float fast_exp(float x){ return __expf(x); }
__device__ __forceinline__ float fast_rcp(float x){ return __builtin_amdgcn_rcpf(x); }
__device__ __forceinline__ float sigmoidf_(float x){ return fast_rcp(1.f + fast_exp(-x)); }
__device__ __forceinline__ float tanhf_(float x){ return 1.f - 2.f*fast_rcp(1.f + fast_exp(2.f*x)); }

__device__ __forceinline__ short f2bf(float f){
  union { float f; unsigned u; } v; v.f = f;
  unsigned r = v.u + 0x7FFFu + ((v.u >> 16) & 1u);   // round-to-nearest-even
  return (short)(r >> 16);
}
__device__ __forceinline__ float bf2f(short s){
  union { unsigned u; float f; } v; v.u = ((unsigned)(unsigned short)s) << 16;
  return v.f;
}

__device__ __forceinline__ float wave_reduce_sum(float v){
  #pragma unroll
  for (int off = 32; off; off >>= 1) v += __shfl_xor(v, off);
  return v;
}

// ---------------------------------------------------------------------------
// Kernel 1: per-student head. Unchanged (lstm is still the top dispatch).
// ---------------------------------------------------------------------------
#define KROW 72
#define PROW 40

__global__ __launch_bounds__(256) void head_kernel(
    const int* __restrict__ uididx, const int* __restrict__ kcodeidx,
    const int* __restrict__ kcode_len, const float* __restrict__ qidemb,
    const int* __restrict__ qid_len, const float* __restrict__ stuE,
    const float* __restrict__ knE,
    const float* __restrict__ T_W1, const float* __restrict__ T_b1,
    const float* __restrict__ T_W2, const float* __restrict__ T_b2,
    const float* __restrict__ A_W1, const float* __restrict__ A_b1,
    const float* __restrict__ A_W2, const float* __restrict__ A_b2,
    short* __restrict__ bvec, float* __restrict__ t_val, float* __restrict__ a_val)
{
  __shared__ __align__(16) short s_kemb[K_*KROW];
  __shared__ __align__(16) short s_kembT[D_*PROW];
  __shared__ __align__(16) short s_p[64*PROW];
  __shared__ float s_stu[D_];
  __shared__ float s_mast[K_];
  __shared__ float s_kmf[K_];
  __shared__ float s_mvec[D_];
  __shared__ float s_avec[D_];
  __shared__ float s_redT[4];
  __shared__ float s_redA[4];

  const int b    = blockIdx.x;
  const int tid  = threadIdx.x;
  const int lane = tid & 63;
  const int w    = tid >> 6;
  const int l15  = lane & 15;
  const int quad = lane >> 4;
  const int klen = kcode_len[b];
  const int qlen = qid_len[b];

  if (tid < D_) s_stu[tid] = stuE[uididx[b]*D_ + tid];
  #pragma unroll
  for (int i = tid; i < 512; i += 256){
    int k = i >> 4, f4 = i & 15;
    const float4 v = *(const float4*)&knE[(size_t)kcodeidx[b*K_ + k]*D_ + f4*4];
    short4 b4; b4.x = f2bf(v.x); b4.y = f2bf(v.y); b4.z = f2bf(v.z); b4.w = f2bf(v.w);
    *(short4*)&s_kemb[k*KROW + f4*4] = b4;
    int d = f4*4;
    s_kembT[(d+0)*PROW + k] = b4.x;
    s_kembT[(d+1)*PROW + k] = b4.y;
    s_kembT[(d+2)*PROW + k] = b4.z;
    s_kembT[(d+3)*PROW + k] = b4.w;
  }
  __syncthreads();

  // mastery: 8 lanes per k, bank-rotated
  {
    int k = tid >> 3, l8 = tid & 7;
    float s = 0.f;
    #pragma unroll
    for (int j = 0; j < 8; ++j){
      int d = l8 + 8*((j + k) & 7);
      s += s_stu[d] * bf2f(s_kemb[k*KROW + d]);
    }
    s += __shfl_xor(s, 1); s += __shfl_xor(s, 2); s += __shfl_xor(s, 4);
    if (l8 == 0){
      float valid = (k < klen) ? 1.f : 0.f;
      s_mast[k] = valid * sigmoidf_(s * 0.2f);
      s_kmf[k]  = valid;
    }
  }
  __syncthreads();

  if (tid < D_){
    float mv = 0.f, av = 0.f;
    #pragma unroll 4
    for (int k = 0; k < K_; ++k){
      float e = bf2f(s_kemb[k*KROW + tid]);
      mv += s_mast[k] * e;
      av += s_kmf[k]  * e;
    }
    s_mvec[tid] = mv; s_avec[tid] = av;
  }
  __syncthreads();

  // ---- attention via MFMA; q A-frags straight from global ----
  {
    const int qrow = w*16 + l15;
    bf16x8 aq[2];
    #pragma unroll
    for (int kt = 0; kt < 2; ++kt){
      if (qrow < qlen){
        const float4 v0 = *(const float4*)&qidemb[((size_t)b*T_ + qrow)*D_ + kt*32 + quad*8];
        const float4 v1 = *(const float4*)&qidemb[((size_t)b*T_ + qrow)*D_ + kt*32 + quad*8 + 4];
        aq[kt][0]=f2bf(v0.x); aq[kt][1]=f2bf(v0.y); aq[kt][2]=f2bf(v0.z); aq[kt][3]=f2bf(v0.w);
        aq[kt][4]=f2bf(v1.x); aq[kt][5]=f2bf(v1.y); aq[kt][6]=f2bf(v1.z); aq[kt][7]=f2bf(v1.w);
      } else {
        aq[kt][0]=0; aq[kt][1]=0; aq[kt][2]=0; aq[kt][3]=0;
        aq[kt][4]=0; aq[kt][5]=0; aq[kt][6]=0; aq[kt][7]=0;
      }
    }
    f32x4 zero = {0.f, 0.f, 0.f, 0.f};
    f32x4 accs[2] = {zero, zero};
    #pragma unroll
    for (int kt = 0; kt < 2; ++kt){
      #pragma unroll
      for (int nt = 0; nt < 2; ++nt){
        bf16x8 bk = *(const bf16x8*)&s_kemb[(nt*16 + l15)*KROW + kt*32 + quad*8];
        accs[nt] = __builtin_amdgcn_mfma_f32_16x16x32_bf16(aq[kt], bk, accs[nt], 0, 0, 0);
      }
    }
    #pragma unroll
    for (int r = 0; r < 4; ++r){
      float v0 = (l15      < klen) ? accs[0][r]*0.15f : -1e9f;
      float v1 = (l15 + 16 < klen) ? accs[1][r]*0.15f : -1e9f;
      float mx = fmaxf(v0, v1);
      #pragma unroll
      for (int off = 1; off < 16; off <<= 1) mx = fmaxf(mx, __shfl_xor(mx, off));
      float e0 = fast_exp(v0 - mx), e1 = fast_exp(v1 - mx);
      float sm = e0 + e1;
      #pragma unroll
      for (int off = 1; off < 16; off <<= 1) sm += __shfl_xor(sm, off);
      float inv = fast_rcp(sm);
      int row = w*16 + quad*4 + r;
      s_p[row*PROW + l15]      = f2bf(e0 * inv);
      s_p[row*PROW + 16 + l15] = f2bf(e1 * inv);
    }
    bf16x8 ap = *(const bf16x8*)&s_p[(w*16 + l15)*PROW + quad*8];
    #pragma unroll
    for (int nt = 0; nt < 4; ++nt){
      bf16x8 bv = *(const bf16x8*)&s_kembT[(nt*16 + l15)*PROW + quad*8];
      f32x4 acco = __builtin_amdgcn_mfma_f32_16x16x32_bf16(ap, bv, zero, 0, 0, 0);
      #pragma unroll
      for (int r = 0; r < 4; ++r){
        int t = w*16 + quad*4 + r;
        if (t < qlen) bvec[((size_t)b*T_ + t)*D_ + nt*16 + l15] = f2bf(acco[r]);
      }
    }
  }

  // ---- both DNNs interleaved ----
  {
    float accT = T_b1[tid];
    float accA = A_b1[tid];
    #pragma unroll 4
    for (int d = 0; d < D_; ++d){
      float mv = s_mvec[d], av = s_avec[d];
      accT += mv * T_W1[d*H_ + tid];
      accA += av * A_W1[d*H_ + tid];
    }
    float termT = tanhf_(accT) * T_W2[tid];
    float termA = tanhf_(accA) * A_W2[tid];
    termT = wave_reduce_sum(termT);
    termA = wave_reduce_sum(termA);
    if (lane == 0){ s_redT[w] = termT; s_redA[w] = termA; }
    __syncthreads();
    if (tid == 0){
      t_val[b] = s_redT[0] + s_redT[1] + s_redT[2] + s_redT[3] + T_b2[0];
      float v = s_redA[0] + s_redA[1] + s_redA[2] + s_redA[3] + A_b2[0];
      a_val[b] = 8.f * (sigmoidf_(fabsf(v)) - 0.5f);
    }
  }
}

// ---------------------------------------------------------------------------
// Kernel 2: MFMA LSTM, R13. Counters show ZERO cross-pipe overlap (VALU 1630 +
// MFMA 760 + LDS 800 + sync 300 ~= 3470 cyc/step): all 8 waves lockstep
// through LDS-phase -> MFMA-phase -> VALU-phase. Changes:
//  (1) x fragments come straight from global into registers (prefetched 2
//      steps ahead) — identical addrs across waves hit L1; removes 2/6
//      ds_reads + all x ds_writes from the shared LDS pipe.
//  (2) gate-major MFMA with activations interleaved: sigmoid(i) runs while
//      f/g/o MFMA chains are still in flight — MFMA pipe hides under the
//      transcendental VALU shadow.
//  (3) LDS is h-only (HROW=280; word-stride ≡ 12 mod 32, same bank pattern
//      as the measured-OK 408 layout).
// Numerics bit-identical to the passing R12 (same fp ops per element).
// ---------------------------------------------------------------------------
#define HROW 280   // shorts/row: h0(128)|h1(128)|pad(24)

__global__ __launch_bounds__(512) void lstm_kernel(
    const short* __restrict__ bvec, const int* __restrict__ qid_len,
    const float* __restrict__ L_Wi, const float* __restrict__ L_Wh,
    const float* __restrict__ L_b,  const float* __restrict__ L_Wo,
    const float* __restrict__ L_bo, const float* __restrict__ t_val,
    const float* __restrict__ a_val, float* __restrict__ out)
{
  __shared__ __align__(16) short s_A[16*HROW];
  __shared__ int s_len[16];

  const int tid  = threadIdx.x;
  const int s0   = blockIdx.x * 16;
  const int w    = tid >> 6;
  const int lane = tid & 63;
  const int l15  = lane & 15;
  const int quad = lane >> 4;

  // Weight fragments (MFMA A operand): col = g*128 + w*16 + l15,
  // k = kt*32 + quad*8 + j.
  bf16x8 wf[4][6];
  f32x4  biasv4[4];   // per-component bias: col = g*128 + w*16 + quad*4 + r
  #pragma unroll
  for (int g = 0; g < 4; ++g){
    const int col = g*128 + w*16 + l15;
    #pragma unroll
    for (int r = 0; r < 4; ++r) biasv4[g][r] = L_b[g*128 + w*16 + quad*4 + r];
    #pragma unroll
    for (int kt = 0; kt < 6; ++kt){
      #pragma unroll
      for (int j = 0; j < 8; ++j){
        int k = kt*32 + quad*8 + j;
        float v = (k < D_) ? L_Wi[k*G4_ + col] : L_Wh[(k-D_)*G4_ + col];
        wf[g][kt][j] = f2bf(v);
      }
    }
  }

  for (int p = tid; p < 16*HROW; p += 512) s_A[p] = 0;
  if (tid < 16) s_len[tid] = qid_len[s0 + tid];
  __syncthreads();

  int maxlen = 0;
  #pragma unroll
  for (int i = 0; i < 16; ++i) maxlen = max(maxlen, s_len[i]);
  const int mylen = s_len[l15];           // one mask per thread (student l15)
  float c_reg[4] = {0.f,0.f,0.f,0.f};
  float h_reg[4] = {0.f,0.f,0.f,0.f};

  // x fragments direct from global (bf16), double-buffered in registers.
  // Thread (l15, quad) needs bvec[student l15][t][quad*8 .. +8] and +32.
  const short* gx = bvec + (size_t)(s0 + l15)*T_*D_ + quad*8;
  bf16x8 xA0 = *(const bf16x8*)(gx);
  bf16x8 xA1 = *(const bf16x8*)(gx + 32);
  bf16x8 xB0 = xA0, xB1 = xA1;
  if (1 < maxlen){ xB0 = *(const bf16x8*)(gx + D_); xB1 = *(const bf16x8*)(gx + D_ + 32); }
  __syncthreads();

#define MF(Aop, Bop, Cop) __builtin_amdgcn_mfma_f32_16x16x32_bf16((Aop), (Bop), (Cop), 0, 0, 0)

#define LSTM_STEP(TI, XB, XC0, XC1) do {                                       \
    const int hb_ = (XB) ^ 1;                                                  \
    const bf16x8 ah0 = *(const bf16x8*)&s_A[l15*HROW + hb_*128 +  0 + quad*8]; \
    const bf16x8 ah1 = *(const bf16x8*)&s_A[l15*HROW + hb_*128 + 32 + quad*8]; \
    const bf16x8 ah2 = *(const bf16x8*)&s_A[l15*HROW + hb_*128 + 64 + quad*8]; \
    const bf16x8 ah3 = *(const bf16x8*)&s_A[l15*HROW + hb_*128 + 96 + quad*8]; \
    f32x4 a0_ = biasv4[0], a1_ = biasv4[1], a2_ = biasv4[2], a3_ = biasv4[3];  \
    a0_ = MF(wf[0][0], XC0, a0_); a0_ = MF(wf[0][1], XC1, a0_);                \
    a1_ = MF(wf[1][0], XC0, a1_); a1_ = MF(wf[1][1], XC1, a1_);                \
    a2_ = MF(wf[2][0], XC0, a2_); a2_ = MF(wf[2][1], XC1, a2_);                \
    a3_ = MF(wf[3][0], XC0, a3_); a3_ = MF(wf[3][1], XC1, a3_);                \
    if ((TI) + 2 < maxlen){                                                    \
      XC0 = *(const bf16x8*)(gx + ((TI)+2)*D_);                                \
      XC1 = *(const bf16x8*)(gx + ((TI)+2)*D_ + 32);                           \
    }                                                                          \
    a0_ = MF(wf[0][2], ah0, a0_); a0_ = MF(wf[0][3], ah1, a0_);                \
    a0_ = MF(wf[0][4], ah2, a0_); a0_ = MF(wf[0][5], ah3, a0_);                \
    a1_ = MF(wf[1][2], ah0, a1_); a1_ = MF(wf[1][3], ah1, a1_);                \
    a1_ = MF(wf[1][4], ah2, a1_); a1_ = MF(wf[1][5], ah3, a1_);                \
    float si_[4], sf_[4], tg_[4], so_[4];                                      \
    _Pragma("unroll") for (int r = 0; r < 4; ++r) si_[r] = sigmoidf_(a0_[r]);  \
    a2_ = MF(wf[2][2], ah0, a2_); a2_ = MF(wf[2][3], ah1, a2_);                \
    a2_ = MF(wf[2][4], ah2, a2_); a2_ = MF(wf[2][5], ah3, a2_);                \
    _Pragma("unroll") for (int r = 0; r < 4; ++r) sf_[r] = sigmoidf_(a1_[r]);  \
    a3_ = MF(wf[3][2], ah0, a3_); a3_ = MF(wf[3][3], ah1, a3_);                \
    a3_ = MF(wf[3][4], ah2, a3_); a3_ = MF(wf[3][5], ah3, a3_);                \
    _Pragma("unroll") for (int r = 0; r < 4; ++r) tg_[r] = tanhf_(a2_[r]);     \
    _Pragma("unroll") for (int r = 0; r < 4; ++r) so_[r] = sigmoidf_(a3_[r]);  \
    const bool upd_ = (TI) < mylen;                                            \
    _Pragma("unroll")                                                          \
    for (int r = 0; r < 4; ++r){                                               \
      float c2 = sf_[r]*c_reg[r] + si_[r]*tg_[r];                              \
      float h2 = so_[r]*tanhf_(c2);                                            \
      c_reg[r] = upd_ ? c2 : c_reg[r];                                         \
      h_reg[r] = upd_ ? h2 : h_reg[r];                                         \
    }                                                                          \
    uint2 hp_;                                                                 \
    hp_.x = (unsigned)(unsigned short)f2bf(h_reg[0])                           \
          | ((unsigned)(unsigned short)f2bf(h_reg[1]) << 16);                  \
    hp_.y = (unsigned)(unsigned short)f2bf(h_reg[2])                           \
          | ((unsigned)(unsigned short)f2bf(h_reg[3]) << 16);                  \
    *(uint2*)&s_A[l15*HROW + (XB)*128 + w*16 + quad*4] = hp_;                  \
    __syncthreads();                                                           \
  } while(0)

  int t = 0;
  for (; t + 1 < maxlen; t += 2){
    LSTM_STEP(t,   0, xA0, xA1);
    LSTM_STEP(t+1, 1, xB0, xB1);
  }
  if (t < maxlen) LSTM_STEP(t, 0, xA0, xA1);
#undef LSTM_STEP
#undef MF

  const int xbLast = (maxlen - 1) & 1;
  for (int s2 = w; s2 < 16; s2 += 8){
    float h0 = bf2f(s_A[s2*HROW + xbLast*128 + lane]);
    float h1 = bf2f(s_A[s2*HROW + xbLast*128 + 64 + lane]);
    float part = h0*L_Wo[lane] + h1*L_Wo[64+lane];
    part = wave_reduce_sum(part);
    if (lane == 0){
      float bb = 8.f * (sigmoidf_(part + L_bo[0]) - 0.5f);
      out[s0+s2] = sigmoidf_(a_val[s0+s2] * (t_val[s0+s2] - bb));
    }
  }
}

// ---------------------------------------------------------------------------
extern "C" void kernel_launch(void* const* d_in, const int* in_sizes, int n_in,
                              void* d_out, int out_size, void* d_ws, size_t ws_size,
                              hipStream_t stream)
{
  (void)in_sizes; (void)n_in; (void)out_size; (void)ws_size;
  const int*   uididx    = (const int*)  d_in[0];
  const int*   kcodeidx  = (const int*)  d_in[1];
  const int*   kcode_len = (const int*)  d_in[2];
  const float* qidemb    = (const float*)d_in[3];
  const int*   qid_len   = (const int*)  d_in[4];
  const float* stuE      = (const float*)d_in[5];
  const float* knE       = (const float*)d_in[6];
  const float* T_W1      = (const float*)d_in[7];
  const float* T_b1      = (const float*)d_in[8];
  const float* T_W2      = (const float*)d_in[9];
  const float* T_b2      = (const float*)d_in[10];
  const float* A_W1      = (const float*)d_in[11];
  const float* A_b1      = (const float*)d_in[12];
  const float* A_W2      = (const float*)d_in[13];
  const float* A_b2      = (const float*)d_in[14];
  const float* L_Wi      = (const float*)d_in[15];
  const float* L_Wh      = (const float*)d_in[16];
  const float* L_b       = (const float*)d_in[17];
  const float* L_Wo      = (const float*)d_in[18];
  const float* L_bo      = (const float*)d_in[19];
  float* out = (float*)d_out;

  short* bvec  = (short*)d_ws;                       // B*T*D bf16 = 26.2 MB
  float* t_val = (float*)(bvec + (size_t)B_*T_*D_);  // B floats
  float* a_val = t_val + B_;                         // B floats

  hipLaunchKernelGGL(head_kernel, dim3(B_), dim3(256), 0, stream,
    uididx, kcodeidx, kcode_len, qidemb, qid_len, stuE, knE,
    T_W1, T_b1, T_W2, T_b2, A_W1, A_b1, A_W2, A_b2,
    bvec, t_val, a_val);

  hipLaunchKernelGGL(lstm_kernel, dim3(B_/16), dim3(512), 0, stream,
    bvec, qid_len, L_Wi, L_Wh, L_b, L_Wo, L_bo, t_val, a_val, out);
}

// Round 3
// 218.679 us; speedup vs baseline: 1.0144x; 1.0021x over previous
//
#include <hip/hip_runtime.h>
#include <math.h>

#define B_  4096
#define T_  50
#define K_  32
#define D_  64
#define H_  256
#define HL_ 128
#define G4_ 512   // 4*HL

typedef __attribute__((ext_vector_type(8))) short bf16x8;
typedef __attribute__((ext_vector_type(4))) float f32x4;

__device__ __forceinline__ float fast_exp(float x){ return __expf(x); }
__device__ __forceinline__ float fast_rcp(float x){ return __builtin_amdgcn_rcpf(x); }
__device__ __forceinline__ float sigmoidf_(float x){ return fast_rcp(1.f + fast_exp(-x)); }
__device__ __forceinline__ float tanhf_(float x){ return 1.f - 2.f*fast_rcp(1.f + fast_exp(2.f*x)); }

__device__ __forceinline__ short f2bf(float f){
  union { float f; unsigned u; } v; v.f = f;
  unsigned r = v.u + 0x7FFFu + ((v.u >> 16) & 1u);   // round-to-nearest-even
  return (short)(r >> 16);
}
__device__ __forceinline__ float bf2f(short s){
  union { unsigned u; float f; } v; v.u = ((unsigned)(unsigned short)s) << 16;
  return v.f;
}

__device__ __forceinline__ float wave_reduce_sum(float v){
  #pragma unroll
  for (int off = 32; off; off >>= 1) v += __shfl_xor(v, off);
  return v;
}

// ---------------------------------------------------------------------------
// Kernel 1: per-student head. Unchanged (lstm is still the top dispatch).
// ---------------------------------------------------------------------------
#define KROW 72
#define PROW 40

__global__ __launch_bounds__(256) void head_kernel(
    const int* __restrict__ uididx, const int* __restrict__ kcodeidx,
    const int* __restrict__ kcode_len, const float* __restrict__ qidemb,
    const int* __restrict__ qid_len, const float* __restrict__ stuE,
    const float* __restrict__ knE,
    const float* __restrict__ T_W1, const float* __restrict__ T_b1,
    const float* __restrict__ T_W2, const float* __restrict__ T_b2,
    const float* __restrict__ A_W1, const float* __restrict__ A_b1,
    const float* __restrict__ A_W2, const float* __restrict__ A_b2,
    short* __restrict__ bvec, float* __restrict__ t_val, float* __restrict__ a_val)
{
  __shared__ __align__(16) short s_kemb[K_*KROW];
  __shared__ __align__(16) short s_kembT[D_*PROW];
  __shared__ __align__(16) short s_p[64*PROW];
  __shared__ float s_stu[D_];
  __shared__ float s_mast[K_];
  __shared__ float s_kmf[K_];
  __shared__ float s_mvec[D_];
  __shared__ float s_avec[D_];
  __shared__ float s_redT[4];
  __shared__ float s_redA[4];

  const int b    = blockIdx.x;
  const int tid  = threadIdx.x;
  const int lane = tid & 63;
  const int w    = tid >> 6;
  const int l15  = lane & 15;
  const int quad = lane >> 4;
  const int klen = kcode_len[b];
  const int qlen = qid_len[b];

  if (tid < D_) s_stu[tid] = stuE[uididx[b]*D_ + tid];
  #pragma unroll
  for (int i = tid; i < 512; i += 256){
    int k = i >> 4, f4 = i & 15;
    const float4 v = *(const float4*)&knE[(size_t)kcodeidx[b*K_ + k]*D_ + f4*4];
    short4 b4; b4.x = f2bf(v.x); b4.y = f2bf(v.y); b4.z = f2bf(v.z); b4.w = f2bf(v.w);
    *(short4*)&s_kemb[k*KROW + f4*4] = b4;
    int d = f4*4;
    s_kembT[(d+0)*PROW + k] = b4.x;
    s_kembT[(d+1)*PROW + k] = b4.y;
    s_kembT[(d+2)*PROW + k] = b4.z;
    s_kembT[(d+3)*PROW + k] = b4.w;
  }
  __syncthreads();

  // mastery: 8 lanes per k, bank-rotated
  {
    int k = tid >> 3, l8 = tid & 7;
    float s = 0.f;
    #pragma unroll
    for (int j = 0; j < 8; ++j){
      int d = l8 + 8*((j + k) & 7);
      s += s_stu[d] * bf2f(s_kemb[k*KROW + d]);
    }
    s += __shfl_xor(s, 1); s += __shfl_xor(s, 2); s += __shfl_xor(s, 4);
    if (l8 == 0){
      float valid = (k < klen) ? 1.f : 0.f;
      s_mast[k] = valid * sigmoidf_(s * 0.2f);
      s_kmf[k]  = valid;
    }
  }
  __syncthreads();

  if (tid < D_){
    float mv = 0.f, av = 0.f;
    #pragma unroll 4
    for (int k = 0; k < K_; ++k){
      float e = bf2f(s_kemb[k*KROW + tid]);
      mv += s_mast[k] * e;
      av += s_kmf[k]  * e;
    }
    s_mvec[tid] = mv; s_avec[tid] = av;
  }
  __syncthreads();

  // ---- attention via MFMA; q A-frags straight from global ----
  {
    const int qrow = w*16 + l15;
    bf16x8 aq[2];
    #pragma unroll
    for (int kt = 0; kt < 2; ++kt){
      if (qrow < qlen){
        const float4 v0 = *(const float4*)&qidemb[((size_t)b*T_ + qrow)*D_ + kt*32 + quad*8];
        const float4 v1 = *(const float4*)&qidemb[((size_t)b*T_ + qrow)*D_ + kt*32 + quad*8 + 4];
        aq[kt][0]=f2bf(v0.x); aq[kt][1]=f2bf(v0.y); aq[kt][2]=f2bf(v0.z); aq[kt][3]=f2bf(v0.w);
        aq[kt][4]=f2bf(v1.x); aq[kt][5]=f2bf(v1.y); aq[kt][6]=f2bf(v1.z); aq[kt][7]=f2bf(v1.w);
      } else {
        aq[kt][0]=0; aq[kt][1]=0; aq[kt][2]=0; aq[kt][3]=0;
        aq[kt][4]=0; aq[kt][5]=0; aq[kt][6]=0; aq[kt][7]=0;
      }
    }
    f32x4 zero = {0.f, 0.f, 0.f, 0.f};
    f32x4 accs[2] = {zero, zero};
    #pragma unroll
    for (int kt = 0; kt < 2; ++kt){
      #pragma unroll
      for (int nt = 0; nt < 2; ++nt){
        bf16x8 bk = *(const bf16x8*)&s_kemb[(nt*16 + l15)*KROW + kt*32 + quad*8];
        accs[nt] = __builtin_amdgcn_mfma_f32_16x16x32_bf16(aq[kt], bk, accs[nt], 0, 0, 0);
      }
    }
    #pragma unroll
    for (int r = 0; r < 4; ++r){
      float v0 = (l15      < klen) ? accs[0][r]*0.15f : -1e9f;
      float v1 = (l15 + 16 < klen) ? accs[1][r]*0.15f : -1e9f;
      float mx = fmaxf(v0, v1);
      #pragma unroll
      for (int off = 1; off < 16; off <<= 1) mx = fmaxf(mx, __shfl_xor(mx, off));
      float e0 = fast_exp(v0 - mx), e1 = fast_exp(v1 - mx);
      float sm = e0 + e1;
      #pragma unroll
      for (int off = 1; off < 16; off <<= 1) sm += __shfl_xor(sm, off);
      float inv = fast_rcp(sm);
      int row = w*16 + quad*4 + r;
      s_p[row*PROW + l15]      = f2bf(e0 * inv);
      s_p[row*PROW + 16 + l15] = f2bf(e1 * inv);
    }
    bf16x8 ap = *(const bf16x8*)&s_p[(w*16 + l15)*PROW + quad*8];
    #pragma unroll
    for (int nt = 0; nt < 4; ++nt){
      bf16x8 bv = *(const bf16x8*)&s_kembT[(nt*16 + l15)*PROW + quad*8];
      f32x4 acco = __builtin_amdgcn_mfma_f32_16x16x32_bf16(ap, bv, zero, 0, 0, 0);
      #pragma unroll
      for (int r = 0; r < 4; ++r){
        int t = w*16 + quad*4 + r;
        if (t < qlen) bvec[((size_t)b*T_ + t)*D_ + nt*16 + l15] = f2bf(acco[r]);
      }
    }
  }

  // ---- both DNNs interleaved ----
  {
    float accT = T_b1[tid];
    float accA = A_b1[tid];
    #pragma unroll 4
    for (int d = 0; d < D_; ++d){
      float mv = s_mvec[d], av = s_avec[d];
      accT += mv * T_W1[d*H_ + tid];
      accA += av * A_W1[d*H_ + tid];
    }
    float termT = tanhf_(accT) * T_W2[tid];
    float termA = tanhf_(accA) * A_W2[tid];
    termT = wave_reduce_sum(termT);
    termA = wave_reduce_sum(termA);
    if (lane == 0){ s_redT[w] = termT; s_redA[w] = termA; }
    __syncthreads();
    if (tid == 0){
      t_val[b] = s_redT[0] + s_redT[1] + s_redT[2] + s_redT[3] + T_b2[0];
      float v = s_redA[0] + s_redA[1] + s_redA[2] + s_redA[3] + A_b2[0];
      a_val[b] = 8.f * (sigmoidf_(fabsf(v)) - 0.5f);
    }
  }
}

// ---------------------------------------------------------------------------
// Kernel 2: MFMA LSTM, R14: BARRIER DE-DRAIN + x-work hoisted off the
// critical path.
//  (1) __syncthreads() emits s_waitcnt vmcnt(0) lgkmcnt(0) — it was draining
//      the x global prefetch every step, exposing HBM latency (FETCH shows
//      bvec reads miss L2). Replaced with raw s_barrier + lgkmcnt(0) only
//      (h ds_writes must drain; x-loads stay in flight across barriers —
//      private registers, no race). sched_barrier(0) fences pin the
//      placement (rule #18).
//  (2) gates(t+1) = b + Wx*x(t+1) + Wh*h(t): the bias+x part is computed at
//      the TAIL of step t (pre-barrier), overlapping other waves' activation
//      tails. Post-barrier chain is now just ds_read h -> 16 h-MFMAs -> acts
//      -> write. Bias folds into C-in of the first x-MFMA (kills 16 movs).
// FP accumulation order preserved exactly (bias,x0,x1,h0..h3) — numerics
// bit-identical to the passing R13.
// ---------------------------------------------------------------------------
#define HROW 280   // shorts/row: h0(128)|h1(128)|pad(24)

__global__ __launch_bounds__(512) void lstm_kernel(
    const short* __restrict__ bvec, const int* __restrict__ qid_len,
    const float* __restrict__ L_Wi, const float* __restrict__ L_Wh,
    const float* __restrict__ L_b,  const float* __restrict__ L_Wo,
    const float* __restrict__ L_bo, const float* __restrict__ t_val,
    const float* __restrict__ a_val, float* __restrict__ out)
{
  __shared__ __align__(16) short s_A[16*HROW];
  __shared__ int s_len[16];

  const int tid  = threadIdx.x;
  const int s0   = blockIdx.x * 16;
  const int w    = tid >> 6;
  const int lane = tid & 63;
  const int l15  = lane & 15;
  const int quad = lane >> 4;

  // Weight fragments (MFMA A operand): col = g*128 + w*16 + l15,
  // k = kt*32 + quad*8 + j.
  bf16x8 wf[4][6];
  f32x4  biasv4[4];   // per-component bias: col = g*128 + w*16 + quad*4 + r
  #pragma unroll
  for (int g = 0; g < 4; ++g){
    const int col = g*128 + w*16 + l15;
    #pragma unroll
    for (int r = 0; r < 4; ++r) biasv4[g][r] = L_b[g*128 + w*16 + quad*4 + r];
    #pragma unroll
    for (int kt = 0; kt < 6; ++kt){
      #pragma unroll
      for (int j = 0; j < 8; ++j){
        int k = kt*32 + quad*8 + j;
        float v = (k < D_) ? L_Wi[k*G4_ + col] : L_Wh[(k-D_)*G4_ + col];
        wf[g][kt][j] = f2bf(v);
      }
    }
  }

  for (int p = tid; p < 16*HROW; p += 512) s_A[p] = 0;
  if (tid < 16) s_len[tid] = qid_len[s0 + tid];
  __syncthreads();

  int maxlen = 0;
  #pragma unroll
  for (int i = 0; i < 16; ++i) maxlen = max(maxlen, s_len[i]);
  const int mylen = s_len[l15];           // one mask per thread (student l15)
  float c_reg[4] = {0.f,0.f,0.f,0.f};
  float h_reg[4] = {0.f,0.f,0.f,0.f};

  // x fragments direct from global (bf16), double-buffered in registers.
  const short* gx = bvec + (size_t)(s0 + l15)*T_*D_ + quad*8;
  bf16x8 xA0 = *(const bf16x8*)(gx);
  bf16x8 xA1 = *(const bf16x8*)(gx + 32);
  bf16x8 xB0 = xA0, xB1 = xA1;
  if (1 < maxlen){ xB0 = *(const bf16x8*)(gx + D_); xB1 = *(const bf16x8*)(gx + D_ + 32); }

#define MF(Aop, Bop, Cop) __builtin_amdgcn_mfma_f32_16x16x32_bf16((Aop), (Bop), (Cop), 0, 0, 0)

  // acc for step 0: bias + Wx*x(0)  (bias as C-in of first MFMA)
  f32x4 a0_ = MF(wf[0][0], xA0, biasv4[0]); a0_ = MF(wf[0][1], xA1, a0_);
  f32x4 a1_ = MF(wf[1][0], xA0, biasv4[1]); a1_ = MF(wf[1][1], xA1, a1_);
  f32x4 a2_ = MF(wf[2][0], xA0, biasv4[2]); a2_ = MF(wf[2][1], xA1, a2_);
  f32x4 a3_ = MF(wf[3][0], xA0, biasv4[3]); a3_ = MF(wf[3][1], xA1, a3_);
  // xA consumed -> reload with x(2)
  if (2 < maxlen){ xA0 = *(const bf16x8*)(gx + 2*D_); xA1 = *(const bf16x8*)(gx + 2*D_ + 32); }
  // s_A already zeroed + synced above; step 0 reads zeros from buffer 1.

#define LSTM_STEP(TI, XB, XN0, XN1) do {                                       \
    const int hb_ = (XB) ^ 1;                                                  \
    const bf16x8 ah0 = *(const bf16x8*)&s_A[l15*HROW + hb_*128 +  0 + quad*8]; \
    const bf16x8 ah1 = *(const bf16x8*)&s_A[l15*HROW + hb_*128 + 32 + quad*8]; \
    const bf16x8 ah2 = *(const bf16x8*)&s_A[l15*HROW + hb_*128 + 64 + quad*8]; \
    const bf16x8 ah3 = *(const bf16x8*)&s_A[l15*HROW + hb_*128 + 96 + quad*8]; \
    a0_ = MF(wf[0][2], ah0, a0_); a0_ = MF(wf[0][3], ah1, a0_);                \
    a0_ = MF(wf[0][4], ah2, a0_); a0_ = MF(wf[0][5], ah3, a0_);                \
    a1_ = MF(wf[1][2], ah0, a1_); a1_ = MF(wf[1][3], ah1, a1_);                \
    a1_ = MF(wf[1][4], ah2, a1_); a1_ = MF(wf[1][5], ah3, a1_);                \
    float si_[4], sf_[4], tg_[4], so_[4];                                      \
    _Pragma("unroll") for (int r = 0; r < 4; ++r) si_[r] = sigmoidf_(a0_[r]);  \
    a2_ = MF(wf[2][2], ah0, a2_); a2_ = MF(wf[2][3], ah1, a2_);                \
    a2_ = MF(wf[2][4], ah2, a2_); a2_ = MF(wf[2][5], ah3, a2_);                \
    _Pragma("unroll") for (int r = 0; r < 4; ++r) sf_[r] = sigmoidf_(a1_[r]);  \
    a3_ = MF(wf[3][2], ah0, a3_); a3_ = MF(wf[3][3], ah1, a3_);                \
    a3_ = MF(wf[3][4], ah2, a3_); a3_ = MF(wf[3][5], ah3, a3_);                \
    _Pragma("unroll") for (int r = 0; r < 4; ++r) tg_[r] = tanhf_(a2_[r]);     \
    _Pragma("unroll") for (int r = 0; r < 4; ++r) so_[r] = sigmoidf_(a3_[r]);  \
    const bool upd_ = (TI) < mylen;                                            \
    _Pragma("unroll")                                                          \
    for (int r = 0; r < 4; ++r){                                               \
      float c2 = sf_[r]*c_reg[r] + si_[r]*tg_[r];                              \
      float h2 = so_[r]*tanhf_(c2);                                            \
      c_reg[r] = upd_ ? c2 : c_reg[r];                                         \
      h_reg[r] = upd_ ? h2 : h_reg[r];                                         \
    }                                                                          \
    uint2 hp_;                                                                 \
    hp_.x = (unsigned)(unsigned short)f2bf(h_reg[0])                           \
          | ((unsigned)(unsigned short)f2bf(h_reg[1]) << 16);                  \
    hp_.y = (unsigned)(unsigned short)f2bf(h_reg[2])                           \
          | ((unsigned)(unsigned short)f2bf(h_reg[3]) << 16);                  \
    *(uint2*)&s_A[l15*HROW + (XB)*128 + w*16 + quad*4] = hp_;                  \
    /* next-step acc prep: bias + Wx*x(TI+1), off the post-barrier path */     \
    a0_ = MF(wf[0][0], XN0, biasv4[0]); a0_ = MF(wf[0][1], XN1, a0_);          \
    a1_ = MF(wf[1][0], XN0, biasv4[1]); a1_ = MF(wf[1][1], XN1, a1_);          \
    a2_ = MF(wf[2][0], XN0, biasv4[2]); a2_ = MF(wf[2][1], XN1, a2_);          \
    a3_ = MF(wf[3][0], XN0, biasv4[3]); a3_ = MF(wf[3][1], XN1, a3_);          \
    if ((TI) + 3 < maxlen){                                                    \
      XN0 = *(const bf16x8*)(gx + ((TI)+3)*D_);                                \
      XN1 = *(const bf16x8*)(gx + ((TI)+3)*D_ + 32);                           \
    }                                                                          \
    __builtin_amdgcn_sched_barrier(0);                                         \
    asm volatile("s_waitcnt lgkmcnt(0)" ::: "memory");                         \
    __builtin_amdgcn_s_barrier();                                              \
    __builtin_amdgcn_sched_barrier(0);                                         \
  } while(0)

  int t = 0;
  for (; t + 1 < maxlen; t += 2){
    LSTM_STEP(t,   0, xB0, xB1);
    LSTM_STEP(t+1, 1, xA0, xA1);
  }
  if (t < maxlen) LSTM_STEP(t, 0, xB0, xB1);
#undef LSTM_STEP
#undef MF

  const int xbLast = (maxlen - 1) & 1;
  for (int s2 = w; s2 < 16; s2 += 8){
    float h0 = bf2f(s_A[s2*HROW + xbLast*128 + lane]);
    float h1 = bf2f(s_A[s2*HROW + xbLast*128 + 64 + lane]);
    float part = h0*L_Wo[lane] + h1*L_Wo[64+lane];
    part = wave_reduce_sum(part);
    if (lane == 0){
      float bb = 8.f * (sigmoidf_(part + L_bo[0]) - 0.5f);
      out[s0+s2] = sigmoidf_(a_val[s0+s2] * (t_val[s0+s2] - bb));
    }
  }
}

// ---------------------------------------------------------------------------
extern "C" void kernel_launch(void* const* d_in, const int* in_sizes, int n_in,
                              void* d_out, int out_size, void* d_ws, size_t ws_size,
                              hipStream_t stream)
{
  (void)in_sizes; (void)n_in; (void)out_size; (void)ws_size;
  const int*   uididx    = (const int*)  d_in[0];
  const int*   kcodeidx  = (const int*)  d_in[1];
  const int*   kcode_len = (const int*)  d_in[2];
  const float* qidemb    = (const float*)d_in[3];
  const int*   qid_len   = (const int*)  d_in[4];
  const float* stuE      = (const float*)d_in[5];
  const float* knE       = (const float*)d_in[6];
  const float* T_W1      = (const float*)d_in[7];
  const float* T_b1      = (const float*)d_in[8];
  const float* T_W2      = (const float*)d_in[9];
  const float* T_b2      = (const float*)d_in[10];
  const float* A_W1      = (const float*)d_in[11];
  const float* A_b1      = (const float*)d_in[12];
  const float* A_W2      = (const float*)d_in[13];
  const float* A_b2      = (const float*)d_in[14];
  const float* L_Wi      = (const float*)d_in[15];
  const float* L_Wh      = (const float*)d_in[16];
  const float* L_b       = (const float*)d_in[17];
  const float* L_Wo      = (const float*)d_in[18];
  const float* L_bo      = (const float*)d_in[19];
  float* out = (float*)d_out;

  short* bvec  = (short*)d_ws;                       // B*T*D bf16 = 26.2 MB
  float* t_val = (float*)(bvec + (size_t)B_*T_*D_);  // B floats
  float* a_val = t_val + B_;                         // B floats

  hipLaunchKernelGGL(head_kernel, dim3(B_), dim3(256), 0, stream,
    uididx, kcodeidx, kcode_len, qidemb, qid_len, stuE, knE,
    T_W1, T_b1, T_W2, T_b2, A_W1, A_b1, A_W2, A_b2,
    bvec, t_val, a_val);

  hipLaunchKernelGGL(lstm_kernel, dim3(B_/16), dim3(512), 0, stream,
    bvec, qid_len, L_Wi, L_Wh, L_b, L_Wo, L_bo, t_val, a_val, out);
}